// Round 13
// baseline (158.831 us; speedup 1.0000x reference)
//
#include <hip/hip_runtime.h>
#include <hip/hip_bf16.h>
#include <cstdint>
#include <cstddef>

#define DIM   768
#define NH    12
#define HD    64
#define BATCH 4
#define SEQ   2048
#define MTOT  (BATCH*SEQ)   // 8192
#define NQKV  (3*DIM)       // 2304

#define LOG2E 1.4426950408889634f

typedef __attribute__((ext_vector_type(8))) short bf16x8;
typedef __attribute__((ext_vector_type(4))) short bf16x4;
typedef __attribute__((ext_vector_type(4))) float f32x4;

__device__ __forceinline__ short f2bf(float f){
  union { __hip_bfloat16 h; short s; } u;
  u.h = __float2bfloat16(f);
  return u.s;
}

#if defined(__HIP_DEVICE_COMPILE__) && __has_builtin(__builtin_amdgcn_exp2f)
#define EXP2(x) __builtin_amdgcn_exp2f(x)
#else
#define EXP2(x) exp2f(x)
#endif

__device__ __forceinline__ f32x4 mfma32(bf16x8 a, bf16x8 b, f32x4 c){
  return __builtin_amdgcn_mfma_f32_16x16x32_bf16(a, b, c, 0, 0, 0);
}

// async global -> LDS, 16B per lane. LDS dest = wave-uniform base + lane*16;
// global source address is per-lane. Increments vmcnt (counted waits below).
__device__ __forceinline__ void gl_lds16(const short* g, short* l){
  __builtin_amdgcn_global_load_lds(
      (const __attribute__((address_space(1))) unsigned int*)g,
      (__attribute__((address_space(3))) unsigned int*)l,
      16, 0, 0);
}

#define VMCNT(N) asm volatile("s_waitcnt vmcnt(" #N ")" ::: "memory")
#define BARRIER() __builtin_amdgcn_s_barrier()

// Fragment-linear image index for element (row m, col k) of a [*,768] matrix.
__device__ __forceinline__ size_t img_idx(int m, int k){
  const int mt = m >> 7, r = m & 127, ks = k >> 5, c = k & 31;
  return ((size_t)(mt*24 + ks))*4096 + (size_t)((r>>6)*2048 + ((r>>4)&3)*512
       + ((r&15) + ((c>>3)<<4))*8 + (c&7));
}

// ---- merged pack kernel -----------------------------------------------------

__global__ __launch_bounds__(256) void pack_all(
    const float* __restrict__ x,
    const float* __restrict__ Wq, const float* __restrict__ Wk,
    const float* __restrict__ Wv, const float* __restrict__ Wo,
    const float* __restrict__ bq, const float* __restrict__ bk,
    const float* __restrict__ bv, const float* __restrict__ mask,
    short* __restrict__ xb, short* __restrict__ wqkv, short* __restrict__ wot,
    float* __restrict__ bqkv, float* __restrict__ mask2)
{
  const int NX4 = MTOT*DIM/4;
  const int NW4 = DIM*DIM/4;
  int gid = blockIdx.x * 256 + threadIdx.x;

  if (gid < NX4){
    float4 v = ((const float4*)x)[gid];
    const int e = gid*4;
    const int m = e / DIM, k = e - m*DIM;   // k multiple of 4
    bf16x4 o;
    o[0] = f2bf(v.x); o[1] = f2bf(v.y); o[2] = f2bf(v.z); o[3] = f2bf(v.w);
    *(bf16x4*)&xb[img_idx(m, k)] = o;       // (k&7)in{0,4} -> 8B aligned
    return;
  }
  gid -= NX4;
  if (gid < 4*NW4){
    const int mat = gid / NW4;
    const int rem = gid - mat*NW4;
    const int e = rem*4;
    const int k = e / DIM, n = e - k*DIM;   // n multiple of 4
    const float* W = (mat == 0) ? Wq : (mat == 1) ? Wk : (mat == 2) ? Wv : Wo;
    const float4 v = *(const float4*)&W[e];
    short* img = (mat < 3) ? wqkv : wot;
    const int ng = (mat < 3) ? mat*DIM + n : n;
    img[img_idx(ng+0, k)] = f2bf(v.x);
    img[img_idx(ng+1, k)] = f2bf(v.y);
    img[img_idx(ng+2, k)] = f2bf(v.z);
    img[img_idx(ng+3, k)] = f2bf(v.w);
    return;
  }
  gid -= 4*NW4;
  if (gid < NQKV)
    bqkv[gid] = (gid < DIM) ? bq[gid] : (gid < 2*DIM) ? bk[gid-DIM] : bv[gid-2*DIM];
  if (gid < BATCH*SEQ)
    mask2[gid] = mask[gid] * LOG2E;
}

// ---- GEMM on fragment-linear images: 128x128 tile, BK=32 --------------------
// Triple-buffered LDS + counted vmcnt + raw s_barrier (unchanged from r12).

template<int MODE>
__global__ __launch_bounds__(256, 3) void gemm_lds(
    const short* __restrict__ Aimg,
    const short* __restrict__ Bimg,
    const float* __restrict__ bias,
    short* __restrict__ o0, short* __restrict__ o1, short* __restrict__ o2,
    float* __restrict__ fo)
{
  __shared__ short ldsA[3*4096];
  __shared__ short ldsB[3*4096];

  const int tid = threadIdx.x;
  const int w  = tid >> 6, l = tid & 63;
  const int lr = l & 15,  lg = l >> 4;
  const int wr = w >> 1,  wc = w & 1;
  const int mt = blockIdx.x, nt = blockIdx.y;
  const int mBase = mt * 128;
  const int nBase = nt * 128;

  const short* gA = Aimg + (size_t)mt*24*4096 + w*512 + l*8;
  const short* gB = Bimg + (size_t)nt*24*4096 + w*512 + l*8;

#define STAGE(BUF, KS) do {                                                \
    gl_lds16(gA + (KS)*4096,        &ldsA[(BUF)*4096 + w*512]);            \
    gl_lds16(gA + (KS)*4096 + 2048, &ldsA[(BUF)*4096 + 2048 + w*512]);     \
    gl_lds16(gB + (KS)*4096,        &ldsB[(BUF)*4096 + w*512]);            \
    gl_lds16(gB + (KS)*4096 + 2048, &ldsB[(BUF)*4096 + 2048 + w*512]);     \
  } while(0)

#define GCOMP(CUR) do {                                                    \
    bf16x8 a[4], b[4];                                                     \
    _Pragma("unroll")                                                      \
    for (int i = 0; i < 4; ++i){                                           \
      a[i] = *(const bf16x8*)&ldsA[(CUR)*4096 + wr*2048 + i*512 + l*8];    \
      b[i] = *(const bf16x8*)&ldsB[(CUR)*4096 + wc*2048 + i*512 + l*8];    \
    }                                                                      \
    _Pragma("unroll")                                                      \
    for (int i = 0; i < 4; ++i)                                            \
      _Pragma("unroll")                                                    \
      for (int j = 0; j < 4; ++j)                                          \
        acc[i][j] = mfma32(a[i], b[j], acc[i][j]);                         \
  } while(0)

  f32x4 acc[4][4] = {};
  STAGE(0, 0);
  STAGE(1, 1);
  int cur = 0;
  for (int kt = 0; kt < 23; ++kt){
    VMCNT(4);
    BARRIER();
    if (kt < 22){
      int nb = cur + 2; if (nb >= 3) nb -= 3;
      STAGE(nb, kt+2);
    }
    GCOMP(cur);
    cur = (cur == 2) ? 0 : cur + 1;
  }
  VMCNT(0);
  BARRIER();
  GCOMP(cur);
#undef STAGE
#undef GCOMP

  if (MODE == 0){
    const int sect  = nBase / DIM;
    const int nloc0 = nBase - sect*DIM + wc*64;
    const float scl = (sect == 0) ? 0.125f*LOG2E : 1.0f;
#pragma unroll
    for (int j = 0; j < 4; ++j){
      const int nl = nloc0 + j*16 + lr;
      const int h = nl >> 6, d = nl & (HD-1);
      const float bn = bias[nBase + wc*64 + j*16 + lr];
#pragma unroll
      for (int i = 0; i < 4; ++i){
        const int m0 = mBase + wr*64 + i*16 + lg*4;   // r = 0..3 consecutive
        const int b_ = m0 >> 11, s0 = m0 & (SEQ-1);
        const int bh = b_*NH + h;
        if (sect == 2){
          const int p0 = (((s0>>2)&3)<<3) | (((s0>>4)&1)<<2);
          const size_t idx = (((size_t)bh*64 + (s0>>5))*4 + (d>>4))*512
                           + ((d&15) + (p0>>3)*16)*8 + (p0&7);
          bf16x4 ov;
#pragma unroll
          for (int r = 0; r < 4; ++r) ov[r] = f2bf((acc[i][j][r] + bn));
          *(bf16x4*)&o2[idx] = ov;
        } else {
#pragma unroll
          for (int r = 0; r < 4; ++r){
            const int s_ = s0 + r;
            const float val = (acc[i][j][r] + bn) * scl;
            if (sect == 0){
              o0[((size_t)bh*SEQ + s_)*HD + d] = f2bf(val);
            } else {
              const size_t idx = (((size_t)bh*64 + (s_>>5))*4
                                  + ((s_>>4)&1)*2 + (d>>5))*512
                               + ((s_&15) + ((d>>3)&3)*16)*8 + (d&7);
              o1[idx] = f2bf(val);
            }
          }
        }
      }
    }
  } else {
#pragma unroll
    for (int j = 0; j < 4; ++j){
      const int n = nBase + wc*64 + j*16 + lr;
      const float bn = bias[n];
#pragma unroll
      for (int i = 0; i < 4; ++i){
#pragma unroll
        for (int r = 0; r < 4; ++r){
          const int m = mBase + wr*64 + i*16 + lg*4 + r;
          fo[(size_t)m * DIM + n] = acc[i][j][r] + bn;
        }
      }
    }
  }
}

// ---- attention: split-k across wave pairs -----------------------------------
// Wave pair p owns q-rows [p*64,p*64+64); wave (p, half) computes the half'th
// 32-key subtile of each staged 64-key block for ALL its 64 q-rows. Exact
// softmax => o/lsum additive over keys: partials combined via one LDS add at
// the end. Per-wave LDS reads halve (the r12 binding pipe). Mask folded into
// the QK accumulator C-init (no VALU adds). lsum = per-lane VALU partials
// (q-row = lane&15 in swapped layout), end-shuffled + pair-reduced.

__global__ __launch_bounds__(256, 3) void attn_kernel(
    const short* __restrict__ q,    // [B,H,S,HD] bf16 (pre-scaled 0.125*log2e)
    const short* __restrict__ kimg, // [BH][64][4][512] bf16 fragment image
    const short* __restrict__ vimg, // [BH][64][4][512] bf16 fragment image
    const float* __restrict__ mask2,// [B,S], mask*log2e
    short* __restrict__ ao)         // A-image bf16
{
  __shared__ short ldsbuf[2][3*4096];   // [0]=K, [1]=V staging; reused for reduce

  const int tid = threadIdx.x;
  const int l = tid & 63, w = tid >> 6;
  const int lr = l & 15, lg = l >> 4;
  const int pair = w >> 1, half = w & 1;
  const int bh = blockIdx.x;            // head-major: pins head to one XCD
  const int b_ = bh / NH;
  const int h  = bh - b_*NH;
  const int qbase = blockIdx.y * 128 + pair * 64;

  short* ldsK = &ldsbuf[0][0];
  short* ldsV = &ldsbuf[1][0];

  const short* qh   = q + (size_t)bh * SEQ * HD;
  const short* kSrc = kimg + (size_t)bh * 64 * 2048 + w*512 + l*8; // per-lane
  const short* vSrc = vimg + (size_t)bh * 64 * 2048 + w*512 + l*8;
  const float* mRow = mask2 + (size_t)b_ * SEQ + lg*4;

  bf16x8 qf[4][2];
#pragma unroll
  for (int t = 0; t < 4; ++t){
    qf[t][0] = *(const bf16x8*)&qh[(size_t)(qbase + t*16 + lr)*HD + lg*8];
    qf[t][1] = *(const bf16x8*)&qh[(size_t)(qbase + t*16 + lr)*HD + 32 + lg*8];
  }

  f32x4 o[4][4] = {};
  float lsum[4] = {0.f, 0.f, 0.f, 0.f};

#define ASTAGE(BUF, ST) do {                                                 \
    gl_lds16(kSrc + (size_t)(ST)*4096,        &ldsK[(BUF)*4096 + w*512]);    \
    gl_lds16(kSrc + (size_t)(ST)*4096 + 2048, &ldsK[(BUF)*4096+2048+w*512]); \
    gl_lds16(vSrc + (size_t)(ST)*4096,        &ldsV[(BUF)*4096 + w*512]);    \
    gl_lds16(vSrc + (size_t)(ST)*4096 + 2048, &ldsV[(BUF)*4096+2048+w*512]); \
  } while(0)

#define ACOMP(ST, CUR) do {                                                  \
    bf16x8 kf[4], vf[4];                                                     \
    _Pragma("unroll")                                                        \
    for (int f = 0; f < 4; ++f){                                             \
      kf[f] = *(const bf16x8*)&ldsK[(CUR)*4096 + half*2048 + f*512 + l*8];   \
      vf[f] = *(const bf16x8*)&ldsV[(CUR)*4096 + half*2048 + f*512 + l*8];   \
    }                                                                        \
    const int koff = (ST)*64 + half*32;                                      \
    const float4 mv0 = *(const float4*)(mRow + koff);                        \
    const float4 mv1 = *(const float4*)(mRow + koff + 16);                   \
    _Pragma("unroll")                                                        \
    for (int t = 0; t < 4; ++t){                                             \
      f32x4 s0 = {mv0.x, mv0.y, mv0.z, mv0.w};                               \
      f32x4 s1 = {mv1.x, mv1.y, mv1.z, mv1.w};                               \
      s0 = mfma32(kf[0], qf[t][0], s0);                                      \
      s0 = mfma32(kf[1], qf[t][1], s0);                                      \
      s1 = mfma32(kf[2], qf[t][0], s1);                                      \
      s1 = mfma32(kf[3], qf[t][1], s1);                                      \
      const float p0 = EXP2(s0[0]);                                          \
      const float p1 = EXP2(s0[1]);                                          \
      const float p2 = EXP2(s0[2]);                                          \
      const float p3 = EXP2(s0[3]);                                          \
      const float p4 = EXP2(s1[0]);                                          \
      const float p5 = EXP2(s1[1]);                                          \
      const float p6 = EXP2(s1[2]);                                          \
      const float p7 = EXP2(s1[3]);                                          \
      lsum[t] += ((p0+p1)+(p2+p3)) + ((p4+p5)+(p6+p7));                      \
      bf16x8 pf;                                                             \
      pf[0]=f2bf(p0); pf[1]=f2bf(p1); pf[2]=f2bf(p2); pf[3]=f2bf(p3);        \
      pf[4]=f2bf(p4); pf[5]=f2bf(p5); pf[6]=f2bf(p6); pf[7]=f2bf(p7);        \
      __builtin_amdgcn_s_setprio(1);                                         \
      o[t][0] = mfma32(vf[0], pf, o[t][0]);                                  \
      o[t][1] = mfma32(vf[1], pf, o[t][1]);                                  \
      o[t][2] = mfma32(vf[2], pf, o[t][2]);                                  \
      o[t][3] = mfma32(vf[3], pf, o[t][3]);                                  \
      __builtin_amdgcn_s_setprio(0);                                         \
    }                                                                        \
  } while(0)

  ASTAGE(0, 0);
  ASTAGE(1, 1);
  int cur = 0;
  for (int st = 0; st < 31; ++st){
    if (st == 0)      VMCNT(4);
    else if (st == 1) VMCNT(6);
    else              VMCNT(8);
    BARRIER();
    if (st < 30){
      int nb = cur + 2; if (nb >= 3) nb -= 3;
      ASTAGE(nb, st+2);
    }
    ACOMP(st, cur);
    cur = (cur == 2) ? 0 : cur + 1;
  }
  VMCNT(2);
  BARRIER();
  ACOMP(31, cur);
#undef ASTAGE
#undef ACOMP

  // lsum: fold the other lg-groups' keys (same q-row lives in lanes with
  // equal lr across the 4 lg groups)
#pragma unroll
  for (int t = 0; t < 4; ++t){
    lsum[t] += __shfl_xor(lsum[t], 16);
    lsum[t] += __shfl_xor(lsum[t], 32);
  }

  // ---- pair reduce: odd wave publishes partials, even wave combines -------
  __syncthreads();   // all staging reads done; LDS reusable
  float* red  = (float*)&ldsbuf[0][0];           // [pair][t][dblk][64lane][4]
  float* redl = ((float*)&ldsbuf[0][0]) + 8192;  // [pair][t][16]
  if (half == 1){
#pragma unroll
    for (int t = 0; t < 4; ++t){
#pragma unroll
      for (int dblk = 0; dblk < 4; ++dblk)
        *(f32x4*)&red[pair*4096 + t*1024 + dblk*256 + l*4] = o[t][dblk];
      if (lg == 0) redl[pair*64 + t*16 + lr] = lsum[t];
    }
  }
  __syncthreads();
  if (half == 0){
#pragma unroll
    for (int t = 0; t < 4; ++t){
      const float ltot = lsum[t] + redl[pair*64 + t*16 + lr];
      const float rinv = 1.f / ltot;
      const int m = b_*SEQ + qbase + t*16 + lr;
      const int mt = m >> 7, r = m & 127;
      short* abase = ao + (size_t)mt*24*4096
                   + (r>>6)*2048 + ((r>>4)&3)*512;
#pragma unroll
      for (int dblk = 0; dblk < 4; ++dblk){
        const f32x4 op = *(const f32x4*)&red[pair*4096 + t*1024 + dblk*256 + l*4];
        bf16x4 ov;
#pragma unroll
        for (int rr = 0; rr < 4; ++rr)
          ov[rr] = f2bf((o[t][dblk][rr] + op[rr]) * rinv);
        const int k = h*64 + dblk*16 + lg*4;
        const int ks = k >> 5, c = k & 31;
        *(bf16x4*)&abase[(size_t)ks*4096 + ((r&15) + ((c>>3)<<4))*8 + (c&7)] = ov;
      }
    }
  }
}

// ---- launch -----------------------------------------------------------------

extern "C" void kernel_launch(void* const* d_in, const int* in_sizes, int n_in,
                              void* d_out, int out_size, void* d_ws, size_t ws_size,
                              hipStream_t stream) {
  const float* x    = (const float*)d_in[0];
  const float* mask = (const float*)d_in[1];
  const float* Wq   = (const float*)d_in[2];
  const float* bq   = (const float*)d_in[3];
  const float* Wk   = (const float*)d_in[4];
  const float* bk   = (const float*)d_in[5];
  const float* Wv   = (const float*)d_in[6];
  const float* bv   = (const float*)d_in[7];
  const float* Wo   = (const float*)d_in[8];
  const float* bo   = (const float*)d_in[9];
  float* out = (float*)d_out;

  char* ws = (char*)d_ws;
  const size_t SZ_XB = (size_t)MTOT * DIM * sizeof(short);
  const size_t SZ_W  = (size_t)DIM * DIM * sizeof(short);

  short* xb   = (short*)ws;            ws += SZ_XB;    // A-image of x
  short* wqkv = (short*)ws;            ws += 3*SZ_W;   // B-image Wq|Wk|Wv
  short* wot  = (short*)ws;            ws += SZ_W;     // B-image Wo
  short* qb   = (short*)ws;            ws += SZ_XB;    // Q row-major head-split
  short* kimg = (short*)ws;            ws += SZ_XB;    // K attn fragment image
  short* vimg = (short*)ws;            ws += SZ_XB;    // V attn fragment image
  short* ao   = (short*)ws;            ws += SZ_XB;    // A-image of attn out
  float* bqkv = (float*)ws;            ws += NQKV * sizeof(float);
  float* mask2= (float*)ws;            ws += (size_t)BATCH*SEQ*sizeof(float);

  const int NPACK = MTOT*DIM/4 + DIM*DIM + BATCH*SEQ;
  pack_all<<<(NPACK + 255)/256, 256, 0, stream>>>(
      x, Wq, Wk, Wv, Wo, bq, bk, bv, mask, xb, wqkv, wot, bqkv, mask2);

  dim3 qkvgrid(MTOT/128, NQKV/128);   // x = m-tile -> XCD pinning of A panels
  gemm_lds<0><<<qkvgrid, 256, 0, stream>>>(xb, wqkv, bqkv, qb, kimg, vimg, nullptr);

  dim3 agrid(BATCH*NH, SEQ/128);
  attn_kernel<<<agrid, 256, 0, stream>>>(qb, kimg, vimg, mask2, ao);

  dim3 ogrid(MTOT/128, DIM/128);
  gemm_lds<1><<<ogrid, 256, 0, stream>>>(ao, wot, bo, nullptr, nullptr, nullptr, out);
}

// Round 14
// 145.600 us; speedup vs baseline: 1.0909x; 1.0909x over previous
//
#include <hip/hip_runtime.h>
#include <hip/hip_bf16.h>
#include <cstdint>
#include <cstddef>

#define DIM   768
#define NH    12
#define HD    64
#define BATCH 4
#define SEQ   2048
#define MTOT  (BATCH*SEQ)   // 8192
#define NQKV  (3*DIM)       // 2304

#define LOG2E 1.4426950408889634f

typedef __attribute__((ext_vector_type(8))) short bf16x8;
typedef __attribute__((ext_vector_type(4))) short bf16x4;
typedef __attribute__((ext_vector_type(4))) float f32x4;

__device__ __forceinline__ short f2bf(float f){
  union { __hip_bfloat16 h; short s; } u;
  u.h = __float2bfloat16(f);
  return u.s;
}

#if defined(__HIP_DEVICE_COMPILE__) && __has_builtin(__builtin_amdgcn_exp2f)
#define EXP2(x) __builtin_amdgcn_exp2f(x)
#else
#define EXP2(x) exp2f(x)
#endif

__device__ __forceinline__ f32x4 mfma32(bf16x8 a, bf16x8 b, f32x4 c){
  return __builtin_amdgcn_mfma_f32_16x16x32_bf16(a, b, c, 0, 0, 0);
}

// async global -> LDS, 16B per lane. LDS dest = wave-uniform base + lane*16;
// global source address is per-lane. Increments vmcnt (counted waits below).
__device__ __forceinline__ void gl_lds16(const short* g, short* l){
  __builtin_amdgcn_global_load_lds(
      (const __attribute__((address_space(1))) unsigned int*)g,
      (__attribute__((address_space(3))) unsigned int*)l,
      16, 0, 0);
}

#define VMCNT(N) asm volatile("s_waitcnt vmcnt(" #N ")" ::: "memory")
#define BARRIER() __builtin_amdgcn_s_barrier()

// Fragment-linear image index for element (row m, col k) of a [*,768] matrix.
__device__ __forceinline__ size_t img_idx(int m, int k){
  const int mt = m >> 7, r = m & 127, ks = k >> 5, c = k & 31;
  return ((size_t)(mt*24 + ks))*4096 + (size_t)((r>>6)*2048 + ((r>>4)&3)*512
       + ((r&15) + ((c>>3)<<4))*8 + (c&7));
}

// ---- merged pack kernel -----------------------------------------------------

__global__ __launch_bounds__(256) void pack_all(
    const float* __restrict__ x,
    const float* __restrict__ Wq, const float* __restrict__ Wk,
    const float* __restrict__ Wv, const float* __restrict__ Wo,
    const float* __restrict__ bq, const float* __restrict__ bk,
    const float* __restrict__ bv, const float* __restrict__ mask,
    short* __restrict__ xb, short* __restrict__ wqkv, short* __restrict__ wot,
    float* __restrict__ bqkv, float* __restrict__ mask2)
{
  const int NX4 = MTOT*DIM/4;
  const int NW4 = DIM*DIM/4;
  int gid = blockIdx.x * 256 + threadIdx.x;

  if (gid < NX4){
    float4 v = ((const float4*)x)[gid];
    const int e = gid*4;
    const int m = e / DIM, k = e - m*DIM;   // k multiple of 4
    bf16x4 o;
    o[0] = f2bf(v.x); o[1] = f2bf(v.y); o[2] = f2bf(v.z); o[3] = f2bf(v.w);
    *(bf16x4*)&xb[img_idx(m, k)] = o;       // (k&7)in{0,4} -> 8B aligned
    return;
  }
  gid -= NX4;
  if (gid < 4*NW4){
    const int mat = gid / NW4;
    const int rem = gid - mat*NW4;
    const int e = rem*4;
    const int k = e / DIM, n = e - k*DIM;   // n multiple of 4
    const float* W = (mat == 0) ? Wq : (mat == 1) ? Wk : (mat == 2) ? Wv : Wo;
    const float4 v = *(const float4*)&W[e];
    short* img = (mat < 3) ? wqkv : wot;
    const int ng = (mat < 3) ? mat*DIM + n : n;
    img[img_idx(ng+0, k)] = f2bf(v.x);
    img[img_idx(ng+1, k)] = f2bf(v.y);
    img[img_idx(ng+2, k)] = f2bf(v.z);
    img[img_idx(ng+3, k)] = f2bf(v.w);
    return;
  }
  gid -= 4*NW4;
  if (gid < NQKV)
    bqkv[gid] = (gid < DIM) ? bq[gid] : (gid < 2*DIM) ? bk[gid-DIM] : bv[gid-2*DIM];
  if (gid < BATCH*SEQ)
    mask2[gid] = mask[gid] * LOG2E;
}

// ---- GEMM on fragment-linear images: 128x128 tile, BK=32 --------------------
// Triple-buffered LDS + counted vmcnt + raw s_barrier (unchanged from r12).

template<int MODE>
__global__ __launch_bounds__(256, 3) void gemm_lds(
    const short* __restrict__ Aimg,
    const short* __restrict__ Bimg,
    const float* __restrict__ bias,
    short* __restrict__ o0, short* __restrict__ o1, short* __restrict__ o2,
    float* __restrict__ fo)
{
  __shared__ short ldsA[3*4096];
  __shared__ short ldsB[3*4096];

  const int tid = threadIdx.x;
  const int w  = tid >> 6, l = tid & 63;
  const int lr = l & 15,  lg = l >> 4;
  const int wr = w >> 1,  wc = w & 1;
  const int mt = blockIdx.x, nt = blockIdx.y;
  const int mBase = mt * 128;
  const int nBase = nt * 128;

  const short* gA = Aimg + (size_t)mt*24*4096 + w*512 + l*8;
  const short* gB = Bimg + (size_t)nt*24*4096 + w*512 + l*8;

#define STAGE(BUF, KS) do {                                                \
    gl_lds16(gA + (KS)*4096,        &ldsA[(BUF)*4096 + w*512]);            \
    gl_lds16(gA + (KS)*4096 + 2048, &ldsA[(BUF)*4096 + 2048 + w*512]);     \
    gl_lds16(gB + (KS)*4096,        &ldsB[(BUF)*4096 + w*512]);            \
    gl_lds16(gB + (KS)*4096 + 2048, &ldsB[(BUF)*4096 + 2048 + w*512]);     \
  } while(0)

#define GCOMP(CUR) do {                                                    \
    bf16x8 a[4], b[4];                                                     \
    _Pragma("unroll")                                                      \
    for (int i = 0; i < 4; ++i){                                           \
      a[i] = *(const bf16x8*)&ldsA[(CUR)*4096 + wr*2048 + i*512 + l*8];    \
      b[i] = *(const bf16x8*)&ldsB[(CUR)*4096 + wc*2048 + i*512 + l*8];    \
    }                                                                      \
    _Pragma("unroll")                                                      \
    for (int i = 0; i < 4; ++i)                                            \
      _Pragma("unroll")                                                    \
      for (int j = 0; j < 4; ++j)                                          \
        acc[i][j] = mfma32(a[i], b[j], acc[i][j]);                         \
  } while(0)

  f32x4 acc[4][4] = {};
  STAGE(0, 0);
  STAGE(1, 1);
  int cur = 0;
  for (int kt = 0; kt < 23; ++kt){
    VMCNT(4);
    BARRIER();
    if (kt < 22){
      int nb = cur + 2; if (nb >= 3) nb -= 3;
      STAGE(nb, kt+2);
    }
    GCOMP(cur);
    cur = (cur == 2) ? 0 : cur + 1;
  }
  VMCNT(0);
  BARRIER();
  GCOMP(cur);
#undef STAGE
#undef GCOMP

  if (MODE == 0){
    const int sect  = nBase / DIM;
    const int nloc0 = nBase - sect*DIM + wc*64;
    const float scl = (sect == 0) ? 0.125f*LOG2E : 1.0f;
#pragma unroll
    for (int j = 0; j < 4; ++j){
      const int nl = nloc0 + j*16 + lr;
      const int h = nl >> 6, d = nl & (HD-1);
      const float bn = bias[nBase + wc*64 + j*16 + lr];
#pragma unroll
      for (int i = 0; i < 4; ++i){
        const int m0 = mBase + wr*64 + i*16 + lg*4;   // r = 0..3 consecutive
        const int b_ = m0 >> 11, s0 = m0 & (SEQ-1);
        const int bh = b_*NH + h;
        if (sect == 2){
          const int p0 = (((s0>>2)&3)<<3) | (((s0>>4)&1)<<2);
          const size_t idx = (((size_t)bh*64 + (s0>>5))*4 + (d>>4))*512
                           + ((d&15) + (p0>>3)*16)*8 + (p0&7);
          bf16x4 ov;
#pragma unroll
          for (int r = 0; r < 4; ++r) ov[r] = f2bf((acc[i][j][r] + bn));
          *(bf16x4*)&o2[idx] = ov;
        } else {
#pragma unroll
          for (int r = 0; r < 4; ++r){
            const int s_ = s0 + r;
            const float val = (acc[i][j][r] + bn) * scl;
            if (sect == 0){
              o0[((size_t)bh*SEQ + s_)*HD + d] = f2bf(val);
            } else {
              const size_t idx = (((size_t)bh*64 + (s_>>5))*4
                                  + ((s_>>4)&1)*2 + (d>>5))*512
                               + ((s_&15) + ((d>>3)&3)*16)*8 + (d&7);
              o1[idx] = f2bf(val);
            }
          }
        }
      }
    }
  } else {
#pragma unroll
    for (int j = 0; j < 4; ++j){
      const int n = nBase + wc*64 + j*16 + lr;
      const float bn = bias[n];
#pragma unroll
      for (int i = 0; i < 4; ++i){
#pragma unroll
        for (int r = 0; r < 4; ++r){
          const int m = mBase + wr*64 + i*16 + lg*4 + r;
          fo[(size_t)m * DIM + n] = acc[i][j][r] + bn;
        }
      }
    }
  }
}

// ---- attention: r12 structure + mask loads hoisted BEFORE stage issue -------
// vmcnt is in-order: r12 loaded mask AFTER ASTAGE(st+2), so consuming the mask
// early in softmax forced retirement of the just-issued stage (full L2 latency
// exposed per step). Fix: load the 4 mask float4s right after the barrier,
// fence, THEN issue the stage. Mask also folded into QK MFMA C-init (saves 16
// VALU adds/wave/step). lsum via mfma(ones,pf); setprio around PV cluster.

__global__ __launch_bounds__(256, 3) void attn_kernel(
    const short* __restrict__ q,    // [B,H,S,HD] bf16 (pre-scaled 0.125*log2e)
    const short* __restrict__ kimg, // [BH][64][4][512] bf16 fragment image
    const short* __restrict__ vimg, // [BH][64][4][512] bf16 fragment image
    const float* __restrict__ mask2,// [B,S], mask*log2e
    short* __restrict__ ao)         // A-image bf16
{
  __shared__ short ldsK[3*4096];
  __shared__ short ldsV[3*4096];

  const int tid = threadIdx.x;
  const int l = tid & 63, w = tid >> 6;
  const int lr = l & 15, lg = l >> 4;
  const int bh = blockIdx.x;            // head-major: pins head to one XCD
  const int b_ = bh / NH;
  const int h  = bh - b_*NH;
  const int qbase = blockIdx.y * 128 + w * 32;

  const short* qh   = q + (size_t)bh * SEQ * HD;
  const short* kSrc = kimg + (size_t)bh * 64 * 2048 + w*512 + l*8; // per-lane
  const short* vSrc = vimg + (size_t)bh * 64 * 2048 + w*512 + l*8;
  const float* mRow = mask2 + (size_t)b_ * SEQ + lg*4;

  bf16x8 qf[2][2];
#pragma unroll
  for (int t = 0; t < 2; ++t){
    qf[t][0] = *(const bf16x8*)&qh[(size_t)(qbase + t*16 + lr)*HD + lg*8];
    qf[t][1] = *(const bf16x8*)&qh[(size_t)(qbase + t*16 + lr)*HD + 32 + lg*8];
  }

  bf16x8 ones;
#pragma unroll
  for (int j = 0; j < 8; ++j) ones[j] = (short)0x3F80;  // bf16 1.0

  f32x4 o[2][4] = {};
  f32x4 lacc[2] = {};

#define ASTAGE(BUF, ST) do {                                                 \
    gl_lds16(kSrc + (size_t)(ST)*4096,        &ldsK[(BUF)*4096 + w*512]);    \
    gl_lds16(kSrc + (size_t)(ST)*4096 + 2048, &ldsK[(BUF)*4096+2048+w*512]); \
    gl_lds16(vSrc + (size_t)(ST)*4096,        &ldsV[(BUF)*4096 + w*512]);    \
    gl_lds16(vSrc + (size_t)(ST)*4096 + 2048, &ldsV[(BUF)*4096+2048+w*512]); \
  } while(0)

  // ACOMP consumes pre-loaded mask vectors MA..MD (keys st*64 .. st*64+63).
#define ACOMP(MA, MB, MC, MD, CUR) do {                                     \
    _Pragma("unroll")                                                        \
    for (int sub = 0; sub < 2; ++sub){                                       \
      bf16x8 kf[4], vf[4];                                                   \
      _Pragma("unroll")                                                      \
      for (int f = 0; f < 4; ++f){                                           \
        kf[f] = *(const bf16x8*)&ldsK[(CUR)*4096 + sub*2048 + f*512 + l*8];  \
        vf[f] = *(const bf16x8*)&ldsV[(CUR)*4096 + sub*2048 + f*512 + l*8];  \
      }                                                                      \
      const float4 m0 = sub ? (MC) : (MA);                                   \
      const float4 m1 = sub ? (MD) : (MB);                                   \
      bf16x8 pf[2];                                                          \
      _Pragma("unroll")                                                      \
      for (int t = 0; t < 2; ++t){                                           \
        f32x4 s0 = {m0.x, m0.y, m0.z, m0.w};                                 \
        f32x4 s1 = {m1.x, m1.y, m1.z, m1.w};                                 \
        s0 = mfma32(kf[0], qf[t][0], s0);                                    \
        s0 = mfma32(kf[1], qf[t][1], s0);                                    \
        s1 = mfma32(kf[2], qf[t][0], s1);                                    \
        s1 = mfma32(kf[3], qf[t][1], s1);                                    \
        const float p0 = EXP2(s0[0]);                                        \
        const float p1 = EXP2(s0[1]);                                        \
        const float p2 = EXP2(s0[2]);                                        \
        const float p3 = EXP2(s0[3]);                                        \
        const float p4 = EXP2(s1[0]);                                        \
        const float p5 = EXP2(s1[1]);                                        \
        const float p6 = EXP2(s1[2]);                                        \
        const float p7 = EXP2(s1[3]);                                        \
        pf[t][0]=f2bf(p0); pf[t][1]=f2bf(p1); pf[t][2]=f2bf(p2); pf[t][3]=f2bf(p3); \
        pf[t][4]=f2bf(p4); pf[t][5]=f2bf(p5); pf[t][6]=f2bf(p6); pf[t][7]=f2bf(p7); \
      }                                                                      \
      __builtin_amdgcn_s_setprio(1);                                         \
      _Pragma("unroll")                                                      \
      for (int dblk = 0; dblk < 4; ++dblk){                                  \
        o[0][dblk] = mfma32(vf[dblk], pf[0], o[0][dblk]);                    \
        o[1][dblk] = mfma32(vf[dblk], pf[1], o[1][dblk]);                    \
      }                                                                      \
      lacc[0] = mfma32(ones, pf[0], lacc[0]);                                \
      lacc[1] = mfma32(ones, pf[1], lacc[1]);                                \
      __builtin_amdgcn_s_setprio(0);                                         \
    }                                                                        \
  } while(0)

  ASTAGE(0, 0);
  ASTAGE(1, 1);
  int cur = 0;
  for (int st = 0; st < 31; ++st){
    VMCNT(4);            // buf[cur] staged (stage st retired; st+1 in flight)
    BARRIER();
    // mask loads BEFORE stage issue: consuming them later only implies
    // retirement of older (already-landed) stages, not the new one.
    const float4 mva = *(const float4*)(mRow + st*64);
    const float4 mvb = *(const float4*)(mRow + st*64 + 16);
    const float4 mvc = *(const float4*)(mRow + st*64 + 32);
    const float4 mvd = *(const float4*)(mRow + st*64 + 48);
    asm volatile("" ::: "memory");   // keep mask loads issued before gl_lds
    if (st < 30){
      int nb = cur + 2; if (nb >= 3) nb -= 3;
      ASTAGE(nb, st+2);
    }
    ACOMP(mva, mvb, mvc, mvd, cur);
    cur = (cur == 2) ? 0 : cur + 1;
  }
  VMCNT(0);
  BARRIER();
  {
    const float4 mva = *(const float4*)(mRow + 31*64);
    const float4 mvb = *(const float4*)(mRow + 31*64 + 16);
    const float4 mvc = *(const float4*)(mRow + 31*64 + 32);
    const float4 mvd = *(const float4*)(mRow + 31*64 + 48);
    ACOMP(mva, mvb, mvc, mvd, cur);
  }
#undef ASTAGE
#undef ACOMP

#pragma unroll
  for (int t = 0; t < 2; ++t){
    const float rinv = 1.f / lacc[t][0];   // lsum[q=lr], resident in every lane
    const int m = b_*SEQ + qbase + t*16 + lr;
    const int mt = m >> 7, r = m & 127;
    short* abase = ao + (size_t)mt*24*4096
                 + (r>>6)*2048 + ((r>>4)&3)*512;
#pragma unroll
    for (int dblk = 0; dblk < 4; ++dblk){
      bf16x4 ov;
#pragma unroll
      for (int rr = 0; rr < 4; ++rr) ov[rr] = f2bf(o[t][dblk][rr] * rinv);
      const int k = h*64 + dblk*16 + lg*4;
      const int ks = k >> 5, c = k & 31;
      *(bf16x4*)&abase[(size_t)ks*4096 + ((r&15) + ((c>>3)<<4))*8 + (c&7)] = ov;
    }
  }
}

// ---- launch -----------------------------------------------------------------

extern "C" void kernel_launch(void* const* d_in, const int* in_sizes, int n_in,
                              void* d_out, int out_size, void* d_ws, size_t ws_size,
                              hipStream_t stream) {
  const float* x    = (const float*)d_in[0];
  const float* mask = (const float*)d_in[1];
  const float* Wq   = (const float*)d_in[2];
  const float* bq   = (const float*)d_in[3];
  const float* Wk   = (const float*)d_in[4];
  const float* bk   = (const float*)d_in[5];
  const float* Wv   = (const float*)d_in[6];
  const float* bv   = (const float*)d_in[7];
  const float* Wo   = (const float*)d_in[8];
  const float* bo   = (const float*)d_in[9];
  float* out = (float*)d_out;

  char* ws = (char*)d_ws;
  const size_t SZ_XB = (size_t)MTOT * DIM * sizeof(short);
  const size_t SZ_W  = (size_t)DIM * DIM * sizeof(short);

  short* xb   = (short*)ws;            ws += SZ_XB;    // A-image of x
  short* wqkv = (short*)ws;            ws += 3*SZ_W;   // B-image Wq|Wk|Wv
  short* wot  = (short*)ws;            ws += SZ_W;     // B-image Wo
  short* qb   = (short*)ws;            ws += SZ_XB;    // Q row-major head-split
  short* kimg = (short*)ws;            ws += SZ_XB;    // K attn fragment image
  short* vimg = (short*)ws;            ws += SZ_XB;    // V attn fragment image
  short* ao   = (short*)ws;            ws += SZ_XB;    // A-image of attn out
  float* bqkv = (float*)ws;            ws += NQKV * sizeof(float);
  float* mask2= (float*)ws;            ws += (size_t)BATCH*SEQ*sizeof(float);

  const int NPACK = MTOT*DIM/4 + DIM*DIM + BATCH*SEQ;
  pack_all<<<(NPACK + 255)/256, 256, 0, stream>>>(
      x, Wq, Wk, Wv, Wo, bq, bk, bv, mask, xb, wqkv, wot, bqkv, mask2);

  dim3 qkvgrid(MTOT/128, NQKV/128);   // x = m-tile -> XCD pinning of A panels
  gemm_lds<0><<<qkvgrid, 256, 0, stream>>>(xb, wqkv, bqkv, qb, kimg, vimg, nullptr);

  dim3 agrid(BATCH*NH, SEQ/128);
  attn_kernel<<<agrid, 256, 0, stream>>>(qb, kimg, vimg, mask2, ao);

  dim3 ogrid(MTOT/128, DIM/128);
  gemm_lds<1><<<ogrid, 256, 0, stream>>>(ao, wot, bo, nullptr, nullptr, nullptr, out);
}